// Round 13
// baseline (277.218 us; speedup 1.0000x reference)
//
#include <hip/hip_runtime.h>
#include <cfloat>

// Problem constants: M=N=64 grid, DIM=512, B=4096, SIGMA=32
#define DIMK 512
#define MN   4096
#define BATCH 4096
#define BK 32
#define NCHUNK 64   // per-row chunks of 64 cols

typedef _Float16 half8_t __attribute__((ext_vector_type(8)));
typedef float f32x4 __attribute__((ext_vector_type(4)));

// async global->LDS, 16B per lane; LDS dest is wave-uniform base + lane*16
#define GLD16(gp, lp) __builtin_amdgcn_global_load_lds( \
    (const __attribute__((address_space(1))) void*)(gp), \
    (__attribute__((address_space(3))) void*)(lp), 16, 0, 0)

// ---------------------------------------------------------------------------
// Convert: X,W fp32 -> f16 (round-to-nearest "hi" only) + exact fp32 row norms.
// 2048 blocks: [0,1024) X (xnorm[row] = ||x||), [1024,2048) W (w2[row] = ||w||^2).
// One wave == one 512-float row.
// ---------------------------------------------------------------------------
__global__ __launch_bounds__(256) void convert_kernel(
        const float* __restrict__ X, const float* __restrict__ W,
        _Float16* __restrict__ Xh, _Float16* __restrict__ Wh,
        float* __restrict__ w2, float* __restrict__ xnorm) {
    const int blk  = blockIdx.x;
    const int t    = threadIdx.x;
    const bool isW = blk >= 1024;
    const float* src = isW ? W : X;
    _Float16* dst  = isW ? Wh : Xh;
    const int rblk = isW ? blk - 1024 : blk;
    const size_t idx = (size_t)rblk * 2048 + (size_t)t * 8;

    float4 v0 = *(const float4*)(src + idx);
    float4 v1 = *(const float4*)(src + idx + 4);
    float v[8] = {v0.x, v0.y, v0.z, v0.w, v1.x, v1.y, v1.z, v1.w};
    half8_t hv;
    float s = 0.f;
#pragma unroll
    for (int e = 0; e < 8; e++) {
        s += v[e] * v[e];
        hv[e] = (_Float16)v[e];
    }
    *(half8_t*)(dst + idx) = hv;

    // one wave == one row: reduce s across 64 lanes
#pragma unroll
    for (int o = 32; o > 0; o >>= 1) s += __shfl_down(s, o);
    if ((t & 63) == 0) {
        int row = rblk * 4 + (t >> 6);
        if (isW) w2[row] = s;
        else     xnorm[row] = __fsqrt_rn(s);
    }
}

// ---------------------------------------------------------------------------
// Approximate score: s~[b,k] = w2[k] - 2*dot(Xh[b],Wh[k])  (single f16 product).
// 128x128 tile, BK=32, dbuf LDS 2x16KB, 1 barrier/iter, 4 blocks/CU.
// Emits per-(row, 64-col chunk) MIN VALUE only (no index) -> pval.
// Error vs exact is bounded in the epilogue (rigorous rescore margin).
// ---------------------------------------------------------------------------
__global__ __launch_bounds__(256, 4) void score_kernel(
        const _Float16* __restrict__ Xh, const _Float16* __restrict__ Wh,
        const float* __restrict__ w2, float* __restrict__ pval) {
    // 32 KB: two buffers, each Ah[4096] | Bh[4096] f16
    __shared__ __align__(16) _Float16 lds[2][8192];

    const int t    = threadIdx.x;
    const int lane = t & 63;
    const int w    = t >> 6;        // wave 0..3
    const int wm   = w >> 1;        // wave m-half
    const int wn   = w & 1;         // wave n-half
    const int m0   = blockIdx.y * 128;
    const int n0   = blockIdx.x * 128;

    f32x4 acc[4][4];
#pragma unroll
    for (int i = 0; i < 4; i++)
#pragma unroll
        for (int j = 0; j < 4; j++) acc[i][j] = (f32x4){0.f, 0.f, 0.f, 0.f};

    // staging: wave w loads 16-row groups (2w, 2w+1) of A and B.
    // within a 1KB group block: lane l -> row (l&15), k-octet (l>>4).
    const int r16 = lane & 15;
    const int kg  = lane >> 4;
    const int b0  = 2 * w, b1 = 2 * w + 1;
    const size_t ko = (size_t)kg * 8;
    const _Float16* gA0 = Xh + (size_t)(m0 + b0 * 16 + r16) * DIMK + ko;
    const _Float16* gA1 = Xh + (size_t)(m0 + b1 * 16 + r16) * DIMK + ko;
    const _Float16* gB0 = Wh + (size_t)(n0 + b0 * 16 + r16) * DIMK + ko;
    const _Float16* gB1 = Wh + (size_t)(n0 + b1 * 16 + r16) * DIMK + ko;
    const int dA0 = b0 * 512 + 0;          // Ah region @0
    const int dA1 = b1 * 512 + 0;
    const int dB0 = 4096 + b0 * 512;       // Bh region @4096
    const int dB1 = 4096 + b1 * 512;

    // prologue: fill buffer 0 with tile k=0
    GLD16(gA0, &lds[0][dA0]);
    GLD16(gA1, &lds[0][dA1]);
    GLD16(gB0, &lds[0][dB0]);
    GLD16(gB1, &lds[0][dB1]);

    int cur = 0;
    for (int k0 = 0; k0 < DIMK; k0 += BK) {
        __syncthreads();               // lds[cur] staged; prior frag reads done
        if (k0 + BK < DIMK) {          // prefetch next tile into alternate buf
            int nk = k0 + BK;
            GLD16(gA0 + nk, &lds[cur ^ 1][dA0]);
            GLD16(gA1 + nk, &lds[cur ^ 1][dA1]);
            GLD16(gB0 + nk, &lds[cur ^ 1][dB0]);
            GLD16(gB1 + nk, &lds[cur ^ 1][dB1]);
        }
        const _Float16* sA = &lds[cur][0];
        const _Float16* sB = &lds[cur][4096];

        half8_t ah[4], bh[4];
#pragma unroll
        for (int i = 0; i < 4; i++) {
            ah[i] = *(const half8_t*)(sA + (wm * 4 + i) * 512 + lane * 8);
            bh[i] = *(const half8_t*)(sB + (wn * 4 + i) * 512 + lane * 8);
        }
#pragma unroll
        for (int i = 0; i < 4; i++)
#pragma unroll
            for (int j = 0; j < 4; j++)
                acc[i][j] = __builtin_amdgcn_mfma_f32_16x16x32_f16(ah[i], bh[j], acc[i][j], 0, 0, 0);
        cur ^= 1;
    }

    // ---- per-row chunk-min over this wave's 64 cols (value only) ----
    // D layout: col = lane&15, row = (lane>>4)*4 + v   (m89/m91 verified)
    const int q  = lane >> 4;
    const int cl = lane & 15;
    float w2v[4];
#pragma unroll
    for (int j = 0; j < 4; j++) w2v[j] = w2[n0 + wn * 64 + j * 16 + cl];
#pragma unroll
    for (int i = 0; i < 4; i++)
#pragma unroll
        for (int v = 0; v < 4; v++) {
            float bv = FLT_MAX;
#pragma unroll
            for (int j = 0; j < 4; j++) {
                float s = w2v[j] - 2.0f * acc[i][j][v];
                bv = fminf(bv, s);
            }
#pragma unroll
            for (int mask = 1; mask <= 8; mask <<= 1)
                bv = fminf(bv, __shfl_xor(bv, mask));
            if (cl == 0) {
                int m = m0 + wm * 64 + i * 16 + q * 4 + v;
                int chunk = blockIdx.x * 2 + wn;
                pval[(size_t)m * NCHUNK + chunk] = bv;
            }
        }
}

// ---------------------------------------------------------------------------
// Epilogue with exact rescore: one block per batch row.
// 1) gmin over the 64 approx chunk mins; rigorous margin
//    m = 2^-9*||x||*sqrt(512) + eps  (f16 product error, Cauchy-Schwarz;
//    w in [0,1) so ||w|| <= sqrt(512)); threshold = gmin + 2m.
// 2) every chunk with chunkmin <= threshold is rescored EXACTLY in fp32 from
//    the original X,W (argmin with lowest-index tie-break; chunks ascending).
// 3) separable Gaussian row written with nontemporal float4 stores.
// ---------------------------------------------------------------------------
__global__ __launch_bounds__(256) void epilogue_kernel(
        const float* __restrict__ pval, const float* __restrict__ w2,
        const float* __restrict__ xnorm,
        const float* __restrict__ X, const float* __restrict__ W,
        const int* __restrict__ decay_p, const int* __restrict__ it_p,
        float* __restrict__ out) {
    __shared__ float xs[512];
    __shared__ float cm[64];
    __shared__ float part[4][64];
    __shared__ float sgmin;
    __shared__ float sbv;
    __shared__ int   sbi;
    __shared__ float tab[128];     // er[64] | ec[64]
    const int row  = blockIdx.x;
    const int t    = threadIdx.x;
    const int lane = t & 63;
    const int w    = t >> 6;

    if (t < 64) cm[t] = pval[(size_t)row * NCHUNK + t];
    // x row -> LDS (512 floats, 2 per thread)
    {
        float2 v = *(const float2*)(X + (size_t)row * DIMK + t * 2);
        xs[t * 2]     = v.x;
        xs[t * 2 + 1] = v.y;
    }
    if (t == 0) { sbv = FLT_MAX; sbi = 0x7FFFFFFF; }
    __syncthreads();
    if (w == 0) {
        float g = cm[lane];
#pragma unroll
        for (int mask = 1; mask <= 32; mask <<= 1)
            g = fminf(g, __shfl_xor(g, mask));
        if (lane == 0) sgmin = g;
    }
    __syncthreads();
    // rigorous rescore threshold (2x safety on the 2^-9*||x||*sqrt(512) bound)
    const float tau = sgmin + 2.0f * (0.05f * xnorm[row] + 0.1f);

    for (int c = 0; c < 64; c++) {
        if (cm[c] <= tau) {            // uniform branch (cm, tau in LDS/uniform)
            const int col = c * 64 + lane;
            const f32x4* wr4 = (const f32x4*)(W + (size_t)col * DIMK + w * 128);
            const float* xb  = xs + w * 128;
            float p = 0.f;
#pragma unroll 8
            for (int d4 = 0; d4 < 32; d4++) {
                f32x4 wv = wr4[d4];
                p += xb[d4 * 4 + 0] * wv[0] + xb[d4 * 4 + 1] * wv[1]
                   + xb[d4 * 4 + 2] * wv[2] + xb[d4 * 4 + 3] * wv[3];
            }
            part[w][lane] = p;
            __syncthreads();
            if (w == 0) {
                float s = w2[col] - 2.0f * (part[0][lane] + part[1][lane]
                                          + part[2][lane] + part[3][lane]);
                int   ii = col;
#pragma unroll
                for (int mask = 1; mask <= 32; mask <<= 1) {
                    float ov = __shfl_xor(s, mask);
                    int   oi = __shfl_xor(ii, mask);
                    if (ov < s || (ov == s && oi < ii)) { s = ov; ii = oi; }
                }
                if (lane == 0 && (s < sbv || (s == sbv && ii < sbi))) {
                    sbv = s; sbi = ii;
                }
            }
            __syncthreads();
        }
    }

    // separable Gaussian tables + row write
    const float lr  = __expf(-(float)(*it_p) / (float)(*decay_p));
    const float so  = 32.0f * lr;          // SIGMA = 32
    const float inv = 1.0f / (so * so);
    const int r = sbi >> 6, c = sbi & 63;
    if (t < 64) {
        float d = (float)(t - r);
        tab[t] = __expf(-d * d * inv);
    } else if (t < 128) {
        float d = (float)(t - 64 - c);
        tab[t] = __expf(-d * d * inv);
    }
    __syncthreads();
    const float* er = tab;
    const float* ec = tab + 64;
    f32x4* orow = (f32x4*)(out + (size_t)row * 4096);
#pragma unroll
    for (int qq = 0; qq < 4; qq++) {
        int f  = qq * 256 + t;             // float4 index in the 4096-row
        int i  = f >> 4;
        int j0 = (f & 15) * 4;
        float e = er[i];
        f32x4 o = {e * ec[j0], e * ec[j0 + 1], e * ec[j0 + 2], e * ec[j0 + 3]};
        __builtin_nontemporal_store(o, orow + f);
    }
}

// ---------------------------------------------------------------------------
extern "C" void kernel_launch(void* const* d_in, const int* in_sizes, int n_in,
                              void* d_out, int out_size, void* d_ws, size_t ws_size,
                              hipStream_t stream) {
    const float* X       = (const float*)d_in[0];   // [4096,512]
    const float* W       = (const float*)d_in[1];   // [4096,512]
    const int*   decay_p = (const int*)d_in[3];
    const int*   it_p    = (const int*)d_in[4];
    float* out = (float*)d_out;

    // ws: Xh (4MB) | Wh (4MB) | w2 16KB | xnorm 16KB | pval 1MB
    _Float16* Xh = (_Float16*)d_ws;
    _Float16* Wh = Xh + (size_t)BATCH * DIMK;
    float*    w2 = (float*)(Wh + (size_t)MN * DIMK);
    float*    xn = w2 + MN;
    float*    pval = xn + BATCH;

    convert_kernel<<<2048, 256, 0, stream>>>(X, W, Xh, Wh, w2, xn);
    score_kernel<<<dim3(32, 32), 256, 0, stream>>>(Xh, Wh, w2, pval);
    epilogue_kernel<<<BATCH, 256, 0, stream>>>(pval, w2, xn, X, W,
                                               decay_p, it_p, out);
}

// Round 14
// 153.273 us; speedup vs baseline: 1.8087x; 1.8087x over previous
//
#include <hip/hip_runtime.h>
#include <cfloat>

// Problem constants: M=N=64 grid, DIM=512, B=4096, SIGMA=32
#define DIMK 512
#define MN   4096
#define BATCH 4096
#define BK 32

typedef _Float16 half8_t __attribute__((ext_vector_type(8)));
typedef float f32x4 __attribute__((ext_vector_type(4)));

// async global->LDS, 16B per lane; LDS dest is wave-uniform base + lane*16
#define GLD16(gp, lp) __builtin_amdgcn_global_load_lds( \
    (const __attribute__((address_space(1))) void*)(gp), \
    (__attribute__((address_space(3))) void*)(lp), 16, 0, 0)

// ---------------------------------------------------------------------------
// Convert: X,W fp32 -> f16 RTN + exact fp32 row norms.
// 2048 blocks: [0,1024) X (xnorm = ||x||), [1024,2048) W (w2 = ||w||^2).
// One wave == one 512-float row.
// ---------------------------------------------------------------------------
__global__ __launch_bounds__(256) void convert_kernel(
        const float* __restrict__ X, const float* __restrict__ W,
        _Float16* __restrict__ Xh, _Float16* __restrict__ Wh,
        float* __restrict__ w2, float* __restrict__ xnorm) {
    const int blk  = blockIdx.x;
    const int t    = threadIdx.x;
    const bool isW = blk >= 1024;
    const float* src = isW ? W : X;
    _Float16* dst  = isW ? Wh : Xh;
    const int rblk = isW ? blk - 1024 : blk;
    const size_t idx = (size_t)rblk * 2048 + (size_t)t * 8;

    float4 v0 = *(const float4*)(src + idx);
    float4 v1 = *(const float4*)(src + idx + 4);
    float v[8] = {v0.x, v0.y, v0.z, v0.w, v1.x, v1.y, v1.z, v1.w};
    half8_t hv;
    float s = 0.f;
#pragma unroll
    for (int e = 0; e < 8; e++) {
        s += v[e] * v[e];
        hv[e] = (_Float16)v[e];
    }
    *(half8_t*)(dst + idx) = hv;
#pragma unroll
    for (int o = 32; o > 0; o >>= 1) s += __shfl_down(s, o);
    if ((t & 63) == 0) {
        int row = rblk * 4 + (t >> 6);
        if (isW) w2[row] = s;
        else     xnorm[row] = __fsqrt_rn(s);
    }
}

// ---------------------------------------------------------------------------
// Approx score GEMM: S[b,k] = w2[k] - 2*dot(Xh[b],Wh[k])  (1 f16 product).
// 128x128 tile, BK=32, dbuf LDS 2x16KB, 1 barrier/iter, 4 blocks/CU.
// Writes the full fp32 S matrix into `S` (aliased to d_out; epilogue
// overwrites row-by-row after reading).
// ---------------------------------------------------------------------------
__global__ __launch_bounds__(256, 4) void score_kernel(
        const _Float16* __restrict__ Xh, const _Float16* __restrict__ Wh,
        const float* __restrict__ w2, float* __restrict__ S) {
    __shared__ __align__(16) _Float16 lds[2][8192];  // Ah[4096] | Bh[4096]

    const int t    = threadIdx.x;
    const int lane = t & 63;
    const int w    = t >> 6;        // wave 0..3
    const int wm   = w >> 1;        // wave m-half
    const int wn   = w & 1;         // wave n-half
    const int m0   = blockIdx.y * 128;
    const int n0   = blockIdx.x * 128;

    f32x4 acc[4][4];
#pragma unroll
    for (int i = 0; i < 4; i++)
#pragma unroll
        for (int j = 0; j < 4; j++) acc[i][j] = (f32x4){0.f, 0.f, 0.f, 0.f};

    const int r16 = lane & 15;
    const int kg  = lane >> 4;
    const int b0  = 2 * w, b1 = 2 * w + 1;
    const size_t ko = (size_t)kg * 8;
    const _Float16* gA0 = Xh + (size_t)(m0 + b0 * 16 + r16) * DIMK + ko;
    const _Float16* gA1 = Xh + (size_t)(m0 + b1 * 16 + r16) * DIMK + ko;
    const _Float16* gB0 = Wh + (size_t)(n0 + b0 * 16 + r16) * DIMK + ko;
    const _Float16* gB1 = Wh + (size_t)(n0 + b1 * 16 + r16) * DIMK + ko;
    const int dA0 = b0 * 512,        dA1 = b1 * 512;
    const int dB0 = 4096 + b0 * 512, dB1 = 4096 + b1 * 512;

    GLD16(gA0, &lds[0][dA0]);
    GLD16(gA1, &lds[0][dA1]);
    GLD16(gB0, &lds[0][dB0]);
    GLD16(gB1, &lds[0][dB1]);

    int cur = 0;
    for (int k0 = 0; k0 < DIMK; k0 += BK) {
        __syncthreads();
        if (k0 + BK < DIMK) {
            int nk = k0 + BK;
            GLD16(gA0 + nk, &lds[cur ^ 1][dA0]);
            GLD16(gA1 + nk, &lds[cur ^ 1][dA1]);
            GLD16(gB0 + nk, &lds[cur ^ 1][dB0]);
            GLD16(gB1 + nk, &lds[cur ^ 1][dB1]);
        }
        const _Float16* sA = &lds[cur][0];
        const _Float16* sB = &lds[cur][4096];

        half8_t ah[4], bh[4];
#pragma unroll
        for (int i = 0; i < 4; i++) {
            ah[i] = *(const half8_t*)(sA + (wm * 4 + i) * 512 + lane * 8);
            bh[i] = *(const half8_t*)(sB + (wn * 4 + i) * 512 + lane * 8);
        }
#pragma unroll
        for (int i = 0; i < 4; i++)
#pragma unroll
            for (int j = 0; j < 4; j++)
                acc[i][j] = __builtin_amdgcn_mfma_f32_16x16x32_f16(ah[i], bh[j], acc[i][j], 0, 0, 0);
        cur ^= 1;
    }

    // ---- write scores. D layout: col = lane&15, row = (lane>>4)*4 + v ----
    const int q  = lane >> 4;
    const int cl = lane & 15;
    float w2v[4];
#pragma unroll
    for (int j = 0; j < 4; j++) w2v[j] = w2[n0 + wn * 64 + j * 16 + cl];
#pragma unroll
    for (int i = 0; i < 4; i++)
#pragma unroll
        for (int v = 0; v < 4; v++) {
            int row = m0 + wm * 64 + i * 16 + q * 4 + v;
            float* Srow = S + (size_t)row * 4096 + n0 + wn * 64;
#pragma unroll
            for (int j = 0; j < 4; j++)
                Srow[j * 16 + cl] = w2v[j] - 2.0f * acc[i][j][v];
        }
}

// ---------------------------------------------------------------------------
// Epilogue: one block per row. Reads own S row from `out`, finds stored
// argmin; rigorous f16-error margin m = 2^-10*||x||*sqrt(512) + slop
// (per-element f16 RTN rel err 2^-11 each operand, Cauchy-Schwarz, w in [0,1)
// so ||w|| <= sqrt(512); + fp32 accumulation slop). Any col with stored
// score <= gmin+2m may be the exact BMU -> rescored exactly in fp32.
// Fast path (typical): no extra candidates -> stored argmin is exact.
// Then writes the separable Gaussian row (overwrites S row).
// ---------------------------------------------------------------------------
__global__ __launch_bounds__(256) void epilogue_kernel(
        const float* __restrict__ w2, const float* __restrict__ xnorm,
        const float* __restrict__ X, const float* __restrict__ W,
        const int* __restrict__ decay_p, const int* __restrict__ it_p,
        float* out) {
    __shared__ float xs[512];
    __shared__ float wval[4];
    __shared__ int   widx[4];
    __shared__ int   list[257];
    __shared__ int   cnt;
    __shared__ float sgmin;
    __shared__ int   sgidx;
    __shared__ int   sfin;
    __shared__ float tab[128];
    const int row  = blockIdx.x;
    const int t    = threadIdx.x;
    const int lane = t & 63;
    const int w    = t >> 6;

    // x row -> LDS; init
    {
        float2 xv = *(const float2*)(X + (size_t)row * DIMK + t * 2);
        xs[2 * t]     = xv.x;
        xs[2 * t + 1] = xv.y;
    }
    if (t == 0) cnt = 0;

    // scan S row (16 values/thread, ascending cols within thread)
    const f32x4* S4 = (const f32x4*)(out + (size_t)row * 4096);
    f32x4 sv[4];
    float bv = FLT_MAX;
    int   bi = 0x7FFFFFFF;
#pragma unroll
    for (int k = 0; k < 4; k++) {
        sv[k] = S4[k * 256 + t];
#pragma unroll
        for (int e = 0; e < 4; e++) {
            int col = k * 1024 + t * 4 + e;
            if (sv[k][e] < bv) { bv = sv[k][e]; bi = col; }
        }
    }
#pragma unroll
    for (int mask = 1; mask <= 32; mask <<= 1) {
        float ov = __shfl_xor(bv, mask);
        int   oi = __shfl_xor(bi, mask);
        if (ov < bv || (ov == bv && oi < bi)) { bv = ov; bi = oi; }
    }
    if (lane == 0) { wval[w] = bv; widx[w] = bi; }
    __syncthreads();
    if (t == 0) {
        float g = wval[0]; int gi = widx[0];
#pragma unroll
        for (int k = 1; k < 4; k++)
            if (wval[k] < g || (wval[k] == g && widx[k] < gi)) { g = wval[k]; gi = widx[k]; }
        sgmin = g; sgidx = gi;
    }
    __syncthreads();

    // rigorous rescore threshold
    const float tau = sgmin + 2.0f * (0.0222f * xnorm[row] + 0.1f);
#pragma unroll
    for (int k = 0; k < 4; k++)
#pragma unroll
        for (int e = 0; e < 4; e++) {
            int col = k * 1024 + t * 4 + e;
            if (sv[k][e] <= tau && col != sgidx) {
                int p = atomicAdd(&cnt, 1);
                if (p < 255) list[p] = col;
            }
        }
    __syncthreads();
    int total = cnt;
    int rr, cc;
    if (total == 0) {                   // fast path: stored argmin is exact BMU
        rr = sgidx >> 6; cc = sgidx & 63;
    } else {                            // exact fp32 rescore of candidates
        if (t == 0) { list[min(total, 255)] = sgidx; }
        __syncthreads();
        total = min(total, 255) + 1;
        float mbv = FLT_MAX;
        int   mbi = 0x7FFFFFFF;
        for (int idx = w; idx < total; idx += 4) {
            int col = list[idx];
            const float* wr = W + (size_t)col * DIMK;
            float p = 0.f;
#pragma unroll
            for (int e = 0; e < 8; e++) p += xs[lane * 8 + e] * wr[lane * 8 + e];
#pragma unroll
            for (int mask = 1; mask <= 32; mask <<= 1) p += __shfl_xor(p, mask);
            float s = w2[col] - 2.0f * p;
            if (s < mbv || (s == mbv && col < mbi)) { mbv = s; mbi = col; }
        }
        if (lane == 0) { wval[w] = mbv; widx[w] = mbi; }
        __syncthreads();
        if (t == 0) {
            float g = wval[0]; int gi = widx[0];
#pragma unroll
            for (int k = 1; k < 4; k++)
                if (wval[k] < g || (wval[k] == g && widx[k] < gi)) { g = wval[k]; gi = widx[k]; }
            sfin = gi;
        }
        __syncthreads();
        rr = sfin >> 6; cc = sfin & 63;
    }

    // separable Gaussian tables + row write (overwrites S row)
    const float lr  = __expf(-(float)(*it_p) / (float)(*decay_p));
    const float so  = 32.0f * lr;          // SIGMA = 32
    const float inv = 1.0f / (so * so);
    if (t < 64) {
        float d = (float)(t - rr);
        tab[t] = __expf(-d * d * inv);
    } else if (t < 128) {
        float d = (float)(t - 64 - cc);
        tab[t] = __expf(-d * d * inv);
    }
    __syncthreads();
    const float* er = tab;
    const float* ec = tab + 64;
    f32x4* orow = (f32x4*)(out + (size_t)row * 4096);
#pragma unroll
    for (int qq = 0; qq < 4; qq++) {
        int f  = qq * 256 + t;
        int i  = f >> 4;
        int j0 = (f & 15) * 4;
        float e = er[i];
        f32x4 o = {e * ec[j0], e * ec[j0 + 1], e * ec[j0 + 2], e * ec[j0 + 3]};
        __builtin_nontemporal_store(o, orow + f);
    }
}

// ---------------------------------------------------------------------------
extern "C" void kernel_launch(void* const* d_in, const int* in_sizes, int n_in,
                              void* d_out, int out_size, void* d_ws, size_t ws_size,
                              hipStream_t stream) {
    const float* X       = (const float*)d_in[0];   // [4096,512]
    const float* W       = (const float*)d_in[1];   // [4096,512]
    const int*   decay_p = (const int*)d_in[3];
    const int*   it_p    = (const int*)d_in[4];
    float* out = (float*)d_out;                     // doubles as S scratch

    // ws: Xh (4MB) | Wh (4MB) | w2 16KB | xnorm 16KB
    _Float16* Xh = (_Float16*)d_ws;
    _Float16* Wh = Xh + (size_t)BATCH * DIMK;
    float*    w2 = (float*)(Wh + (size_t)MN * DIMK);
    float*    xn = w2 + MN;

    convert_kernel<<<2048, 256, 0, stream>>>(X, W, Xh, Wh, w2, xn);
    score_kernel<<<dim3(32, 32), 256, 0, stream>>>(Xh, Wh, w2, out);
    epilogue_kernel<<<BATCH, 256, 0, stream>>>(w2, xn, X, W, decay_p, it_p, out);
}

// Round 15
// 144.800 us; speedup vs baseline: 1.9145x; 1.0585x over previous
//
#include <hip/hip_runtime.h>
#include <cfloat>

// Problem constants: M=N=64 grid, DIM=512, B=4096, SIGMA=32
#define DIMK 512
#define MN   4096
#define BATCH 4096
#define BK 32
#define NGRP 1024   // 4-column groups per row

typedef _Float16 half8_t __attribute__((ext_vector_type(8)));
typedef float f32x4 __attribute__((ext_vector_type(4)));

// async global->LDS, 16B per lane; LDS dest is wave-uniform base + lane*16
#define GLD16(gp, lp) __builtin_amdgcn_global_load_lds( \
    (const __attribute__((address_space(1))) void*)(gp), \
    (__attribute__((address_space(3))) void*)(lp), 16, 0, 0)

// ---------------------------------------------------------------------------
// Convert: X,W fp32 -> f16 RTN + exact fp32 row norms. (unchanged from R14)
// ---------------------------------------------------------------------------
__global__ __launch_bounds__(256) void convert_kernel(
        const float* __restrict__ X, const float* __restrict__ W,
        _Float16* __restrict__ Xh, _Float16* __restrict__ Wh,
        float* __restrict__ w2, float* __restrict__ xnorm) {
    const int blk  = blockIdx.x;
    const int t    = threadIdx.x;
    const bool isW = blk >= 1024;
    const float* src = isW ? W : X;
    _Float16* dst  = isW ? Wh : Xh;
    const int rblk = isW ? blk - 1024 : blk;
    const size_t idx = (size_t)rblk * 2048 + (size_t)t * 8;

    float4 v0 = *(const float4*)(src + idx);
    float4 v1 = *(const float4*)(src + idx + 4);
    float v[8] = {v0.x, v0.y, v0.z, v0.w, v1.x, v1.y, v1.z, v1.w};
    half8_t hv;
    float s = 0.f;
#pragma unroll
    for (int e = 0; e < 8; e++) {
        s += v[e] * v[e];
        hv[e] = (_Float16)v[e];
    }
    *(half8_t*)(dst + idx) = hv;
#pragma unroll
    for (int o = 32; o > 0; o >>= 1) s += __shfl_down(s, o);
    if ((t & 63) == 0) {
        int row = rblk * 4 + (t >> 6);
        if (isW) w2[row] = s;
        else     xnorm[row] = __fsqrt_rn(s);
    }
}

// ---------------------------------------------------------------------------
// Approx score GEMM, group-min output: for each row, 1024 mins over 4-col
// groups of s~[b,k] = w2[k] - 2*dot(Xh,Wh). Group-mins land in the FIRST 4KB
// of row b's own region of d_out (self-aliasing: epilogue block b reads only
// its own row bytes before overwriting them — same bijection as R14).
// 128x128 tile, BK=32, dbuf LDS 2x16KB, 1 barrier/iter, 4 blocks/CU.
// ---------------------------------------------------------------------------
__global__ __launch_bounds__(256, 4) void score_kernel(
        const _Float16* __restrict__ Xh, const _Float16* __restrict__ Wh,
        const float* __restrict__ w2, float* __restrict__ Gm /* = d_out */) {
    __shared__ __align__(16) _Float16 lds[2][8192];  // Ah[4096] | Bh[4096]

    const int t    = threadIdx.x;
    const int lane = t & 63;
    const int w    = t >> 6;        // wave 0..3
    const int wm   = w >> 1;        // wave m-half
    const int wn   = w & 1;         // wave n-half
    const int m0   = blockIdx.y * 128;
    const int n0   = blockIdx.x * 128;

    f32x4 acc[4][4];
#pragma unroll
    for (int i = 0; i < 4; i++)
#pragma unroll
        for (int j = 0; j < 4; j++) acc[i][j] = (f32x4){0.f, 0.f, 0.f, 0.f};

    const int r16 = lane & 15;
    const int kg  = lane >> 4;
    const int b0  = 2 * w, b1 = 2 * w + 1;
    const size_t ko = (size_t)kg * 8;
    const _Float16* gA0 = Xh + (size_t)(m0 + b0 * 16 + r16) * DIMK + ko;
    const _Float16* gA1 = Xh + (size_t)(m0 + b1 * 16 + r16) * DIMK + ko;
    const _Float16* gB0 = Wh + (size_t)(n0 + b0 * 16 + r16) * DIMK + ko;
    const _Float16* gB1 = Wh + (size_t)(n0 + b1 * 16 + r16) * DIMK + ko;
    const int dA0 = b0 * 512,        dA1 = b1 * 512;
    const int dB0 = 4096 + b0 * 512, dB1 = 4096 + b1 * 512;

    GLD16(gA0, &lds[0][dA0]);
    GLD16(gA1, &lds[0][dA1]);
    GLD16(gB0, &lds[0][dB0]);
    GLD16(gB1, &lds[0][dB1]);

    int cur = 0;
    for (int k0 = 0; k0 < DIMK; k0 += BK) {
        __syncthreads();
        if (k0 + BK < DIMK) {
            int nk = k0 + BK;
            GLD16(gA0 + nk, &lds[cur ^ 1][dA0]);
            GLD16(gA1 + nk, &lds[cur ^ 1][dA1]);
            GLD16(gB0 + nk, &lds[cur ^ 1][dB0]);
            GLD16(gB1 + nk, &lds[cur ^ 1][dB1]);
        }
        const _Float16* sA = &lds[cur][0];
        const _Float16* sB = &lds[cur][4096];

        half8_t ah[4], bh[4];
#pragma unroll
        for (int i = 0; i < 4; i++) {
            ah[i] = *(const half8_t*)(sA + (wm * 4 + i) * 512 + lane * 8);
            bh[i] = *(const half8_t*)(sB + (wn * 4 + i) * 512 + lane * 8);
        }
#pragma unroll
        for (int i = 0; i < 4; i++)
#pragma unroll
            for (int j = 0; j < 4; j++)
                acc[i][j] = __builtin_amdgcn_mfma_f32_16x16x32_f16(ah[i], bh[j], acc[i][j], 0, 0, 0);
        cur ^= 1;
    }

    // ---- 4-col group mins. D layout: col = lane&15, row = (lane>>4)*4+v ----
    const int q   = lane >> 4;
    const int cl  = lane & 15;
    const int gb  = (n0 >> 2) + wn * 16;      // group base for this wave
    float w2v[4];
#pragma unroll
    for (int j = 0; j < 4; j++) w2v[j] = w2[n0 + wn * 64 + j * 16 + cl];
#pragma unroll
    for (int i = 0; i < 4; i++)
#pragma unroll
        for (int v = 0; v < 4; v++) {
            const int row = m0 + wm * 64 + i * 16 + q * 4 + v;
            float* grow = Gm + (size_t)row * 4096 + gb;
#pragma unroll
            for (int j = 0; j < 4; j++) {
                float s = w2v[j] - 2.0f * acc[i][j][v];
                s = fminf(s, __shfl_xor(s, 1));
                s = fminf(s, __shfl_xor(s, 2));
                if ((cl & 3) == 0) grow[j * 4 + (cl >> 2)] = s;
            }
        }
}

// ---------------------------------------------------------------------------
// Epilogue: one block per row. Reads its own 4KB of group-mins from d_out,
// computes gmin + rigorous margin (tau = gmin + 2*(2^-10*||x||*sqrt(512)
// + slop); w in [0,1) so ||w|| <= sqrt(512)), collects qualifying groups
// (always >= 1), rescores their columns EXACTLY in fp32 (one wave per col,
// coalesced 2KB W reads), exact argmin with lowest-index tie-break. Then
// overwrites the row with the separable Gaussian (nontemporal stores).
// ---------------------------------------------------------------------------
__global__ __launch_bounds__(256) void epilogue_kernel(
        const float* __restrict__ w2, const float* __restrict__ xnorm,
        const float* __restrict__ X, const float* __restrict__ W,
        const int* __restrict__ decay_p, const int* __restrict__ it_p,
        float* out) {
    __shared__ float xs[512];
    __shared__ int   list[NGRP];
    __shared__ int   cnt;
    __shared__ float wmin[4];
    __shared__ float svv[4];
    __shared__ int   svi[4];
    __shared__ float sbv;
    __shared__ int   sbi;
    __shared__ float tab[128];
    const int row  = blockIdx.x;
    const int t    = threadIdx.x;
    const int lane = t & 63;
    const int w    = t >> 6;

    // x row -> LDS; init
    {
        float2 xv = *(const float2*)(X + (size_t)row * DIMK + t * 2);
        xs[2 * t]     = xv.x;
        xs[2 * t + 1] = xv.y;
    }
    if (t == 0) { cnt = 0; sbv = FLT_MAX; sbi = 0x7FFFFFFF; }

    // group-mins: 4 per thread
    f32x4 gm = *((const f32x4*)(out + (size_t)row * 4096) + t);
    float g = fminf(fminf(gm[0], gm[1]), fminf(gm[2], gm[3]));
#pragma unroll
    for (int mask = 1; mask <= 32; mask <<= 1)
        g = fminf(g, __shfl_xor(g, mask));
    if (lane == 0) wmin[w] = g;
    __syncthreads();
    const float gmin = fminf(fminf(wmin[0], wmin[1]), fminf(wmin[2], wmin[3]));
    const float tau  = gmin + 2.0f * (0.0222f * xnorm[row] + 0.1f);

    // collect qualifying groups (unordered; tie-break handled by explicit col)
#pragma unroll
    for (int e = 0; e < 4; e++)
        if (gm[e] <= tau) list[atomicAdd(&cnt, 1)] = t * 4 + e;
    __syncthreads();
    const int total = cnt;            // >= 1 always (gmin's group qualifies)

    // exact fp32 rescore: wave w handles col 4*g + w of each listed group
    for (int idx = 0; idx < total; idx++) {
        const int col = list[idx] * 4 + w;
        const float* wr = W + (size_t)col * DIMK;
        float p = 0.f;
#pragma unroll
        for (int e = 0; e < 8; e++) p += xs[lane * 8 + e] * wr[lane * 8 + e];
#pragma unroll
        for (int mask = 1; mask <= 32; mask <<= 1) p += __shfl_xor(p, mask);
        if (lane == 0) {
            svv[w] = w2[col] - 2.0f * p;
            svi[w] = col;
        }
        __syncthreads();
        if (t == 0) {
#pragma unroll
            for (int k = 0; k < 4; k++) {
                float s = svv[k]; int c = svi[k];
                if (s < sbv || (s == sbv && c < sbi)) { sbv = s; sbi = c; }
            }
        }
        __syncthreads();
    }

    // separable Gaussian tables + row write (overwrites group-mins)
    const float lr  = __expf(-(float)(*it_p) / (float)(*decay_p));
    const float so  = 32.0f * lr;          // SIGMA = 32
    const float inv = 1.0f / (so * so);
    const int rr = sbi >> 6, cc = sbi & 63;
    if (t < 64) {
        float d = (float)(t - rr);
        tab[t] = __expf(-d * d * inv);
    } else if (t < 128) {
        float d = (float)(t - 64 - cc);
        tab[t] = __expf(-d * d * inv);
    }
    __syncthreads();
    const float* er = tab;
    const float* ec = tab + 64;
    f32x4* orow = (f32x4*)(out + (size_t)row * 4096);
#pragma unroll
    for (int qq = 0; qq < 4; qq++) {
        int f  = qq * 256 + t;
        int i  = f >> 4;
        int j0 = (f & 15) * 4;
        float e = er[i];
        f32x4 o = {e * ec[j0], e * ec[j0 + 1], e * ec[j0 + 2], e * ec[j0 + 3]};
        __builtin_nontemporal_store(o, orow + f);
    }
}

// ---------------------------------------------------------------------------
extern "C" void kernel_launch(void* const* d_in, const int* in_sizes, int n_in,
                              void* d_out, int out_size, void* d_ws, size_t ws_size,
                              hipStream_t stream) {
    const float* X       = (const float*)d_in[0];   // [4096,512]
    const float* W       = (const float*)d_in[1];   // [4096,512]
    const int*   decay_p = (const int*)d_in[3];
    const int*   it_p    = (const int*)d_in[4];
    float* out = (float*)d_out;                     // doubles as group-min scratch

    // ws: Xh (4MB) | Wh (4MB) | w2 16KB | xnorm 16KB
    _Float16* Xh = (_Float16*)d_ws;
    _Float16* Wh = Xh + (size_t)BATCH * DIMK;
    float*    w2 = (float*)(Wh + (size_t)MN * DIMK);
    float*    xn = w2 + MN;

    convert_kernel<<<2048, 256, 0, stream>>>(X, W, Xh, Wh, w2, xn);
    score_kernel<<<dim3(32, 32), 256, 0, stream>>>(Xh, Wh, w2, out);
    epilogue_kernel<<<BATCH, 256, 0, stream>>>(w2, xn, X, W, decay_p, it_p, out);
}